// Round 9
// baseline (50.173 us; speedup 1.0000x reference)
//
#include <hip/hip_runtime.h>
#include <hip/hip_bf16.h>
#include <math.h>

// ---------------------------------------------------------------------------
// HybridQuantumLinear, fully MFMA-ized:
//   out[b,:] = P[b,:] . M,  P_i = |(psi_in . U^T)_i|^2,
//   M[i][o] = sum_q sign_q(i) * W_out[o][q]   (batch-invariant, hi/lo bf16)
//   k01: blocks 0..63   build U -> Bt[512][288] bf16 (row n=2i+c, col j)
//        blocks 64..71  build Mt_hi/Mt_lo[512][288] bf16 (row o, col i)
//        blocks 72..    encode: enc=tanh(x@W_in^T)*pi -> psi (REAL product
//                       state, bf16, stride 288). One wave per batch row.
//   k2:  256 blocks x 4 waves; 32 rows/block; wave -> 128 cols.
//        G2: psiout = psi @ Bt^T (MFMA, K=256) ; P = re^2+im^2 (pair shfl)
//        -> P_lds bf16 ; G3: out = P @ M (MFMA, K=256, hi+lo) -> direct store.
// Amp index i: bit(7-q) = qubit q. In U-build, i = lane*4 + k.
// Strides 288 shorts (576 B) vs L2-channel camping (R8: -1.3us).
// ---------------------------------------------------------------------------

#define BTS 288    // Bt row stride (shorts)
#define MTS 288    // Mt row stride (shorts)
#define PSIS 288   // psi row stride (shorts)
#define PLS 296    // P_lds row stride (shorts), 592 B: de-conflicts kg rows

typedef __attribute__((ext_vector_type(8))) short bf16x8;
typedef __attribute__((ext_vector_type(4))) float f32x4;

static __device__ __forceinline__ unsigned short f2bf(float f) {
  __hip_bfloat16 h = __float2bfloat16(f);
  return *reinterpret_cast<unsigned short*>(&h);
}
static __device__ __forceinline__ float bf2f(unsigned short u) {
  unsigned int v = ((unsigned int)u) << 16;
  float r;
  __builtin_memcpy(&r, &v, 4);
  return r;
}

__device__ __forceinline__ float2 shfl_xor_f2(float2 v, int m) {
  float2 r;
  r.x = __shfl_xor(v.x, m, 64);
  r.y = __shfl_xor(v.y, m, 64);
  return r;
}
__device__ __forceinline__ float2 cfma(float2 u, float2 v, float2 acc) {
  acc.x = fmaf(u.x, v.x, fmaf(-u.y, v.y, acc.x));
  acc.y = fmaf(u.x, v.y, fmaf(u.y, v.x, acc.y));
  return acc;
}

__device__ __forceinline__ void apply_gate(float2 (&a)[4], int q, float2 u00,
                                           float2 u01, float2 u10, float2 u11,
                                           int lane) {
  const float2 z0 = make_float2(0.f, 0.f);
  if (q == 7) {
    float2 n0 = cfma(u00, a[0], cfma(u01, a[1], z0));
    float2 n1 = cfma(u10, a[0], cfma(u11, a[1], z0));
    float2 n2 = cfma(u00, a[2], cfma(u01, a[3], z0));
    float2 n3 = cfma(u10, a[2], cfma(u11, a[3], z0));
    a[0] = n0; a[1] = n1; a[2] = n2; a[3] = n3;
  } else if (q == 6) {
    float2 n0 = cfma(u00, a[0], cfma(u01, a[2], z0));
    float2 n2 = cfma(u10, a[0], cfma(u11, a[2], z0));
    float2 n1 = cfma(u00, a[1], cfma(u01, a[3], z0));
    float2 n3 = cfma(u10, a[1], cfma(u11, a[3], z0));
    a[0] = n0; a[1] = n1; a[2] = n2; a[3] = n3;
  } else {
    int m = 1 << (5 - q);
    bool b = (lane >> (5 - q)) & 1;
    float2 ca = b ? u11 : u00;
    float2 cp = b ? u10 : u01;
    #pragma unroll
    for (int k = 0; k < 4; ++k) {
      float2 p = shfl_xor_f2(a[k], m);
      a[k] = cfma(ca, a[k], cfma(cp, p, z0));
    }
  }
}

__device__ __forceinline__ void apply_cnot(float2 (&a)[4], int q, int lane) {
  if (q <= 4) {
    int m = 1 << (4 - q);
    bool ctrl = (lane >> (5 - q)) & 1;
    #pragma unroll
    for (int k = 0; k < 4; ++k) {
      float2 p = shfl_xor_f2(a[k], m);
      a[k].x = ctrl ? p.x : a[k].x;
      a[k].y = ctrl ? p.y : a[k].y;
    }
  } else if (q == 5) {
    bool ct = lane & 1;
    float2 n0 = ct ? a[2] : a[0];
    float2 n1 = ct ? a[3] : a[1];
    float2 n2 = ct ? a[0] : a[2];
    float2 n3 = ct ? a[1] : a[3];
    a[0] = n0; a[1] = n1; a[2] = n2; a[3] = n3;
  } else {
    float2 t = a[2]; a[2] = a[3]; a[3] = t;
  }
}

__global__ __launch_bounds__(256) void k01_kernel(
    const float* __restrict__ x, const float* __restrict__ W_in,
    const float* __restrict__ W_out, const float* __restrict__ theta,
    __hip_bfloat16* __restrict__ Bt, unsigned short* __restrict__ Mthi,
    unsigned short* __restrict__ Mtlo, __hip_bfloat16* __restrict__ psi,
    int B) {
  __shared__ float mats[32 * 8];
  const int tid = threadIdx.x;
  const int lane = tid & 63;

  if (blockIdx.x < 64) {
    // ---------------- U-build ----------------
    if (tid < 32) {
      int l = tid >> 3, q = tid & 7;
      const float* th = theta + (l * 8 + q) * 3;
      float h1 = 0.5f * th[0], h2 = 0.5f * th[1], h3 = 0.5f * th[2];
      float c1 = cosf(h1), s1 = sinf(h1);
      float c2 = cosf(h2), s2 = sinf(h2);
      float c3 = cosf(h3), s3 = sinf(h3);
      float m00r = c2 * c1, m00i = s2 * s1;
      float m01r = -s2 * c1, m01i = -c2 * s1;
      float m10r = s2 * c1, m10i = -c2 * s1;
      float m11r = c1 * c2, m11i = -s1 * s2;
      float* o = &mats[tid * 8];
      o[0] = c3 * m00r + s3 * m00i;  o[1] = c3 * m00i - s3 * m00r;
      o[2] = c3 * m01r + s3 * m01i;  o[3] = c3 * m01i - s3 * m01r;
      o[4] = c3 * m10r - s3 * m10i;  o[5] = c3 * m10i + s3 * m10r;
      o[6] = c3 * m11r - s3 * m11i;  o[7] = c3 * m11i + s3 * m11r;
    }
    __syncthreads();

    const int j = blockIdx.x * 4 + (tid >> 6);  // basis column
    float2 a[4];
    #pragma unroll
    for (int k = 0; k < 4; ++k)
      a[k] = make_float2((lane * 4 + k == j) ? 1.f : 0.f, 0.f);

    #pragma unroll
    for (int l = 0; l < 4; ++l) {
      #pragma unroll
      for (int q = 0; q < 8; ++q) {
        const float* m = &mats[(l * 8 + q) * 8];
        apply_gate(a, q, make_float2(m[0], m[1]), make_float2(m[2], m[3]),
                   make_float2(m[4], m[5]), make_float2(m[6], m[7]), lane);
      }
      #pragma unroll
      for (int i = (l & 1); i < 7; i += 2) apply_cnot(a, i, lane);
    }
    #pragma unroll
    for (int k = 0; k < 4; ++k) {
      int n0 = (lane * 4 + k) * 2;
      Bt[n0 * BTS + j]       = __float2bfloat16(a[k].x);
      Bt[(n0 + 1) * BTS + j] = __float2bfloat16(a[k].y);
    }
    return;
  }

  if (blockIdx.x < 72) {
    // ---------------- Mt build: Mt[o][i] = sum_q sign_q(i) W_out[o][q] -----
    const int bb = (int)blockIdx.x - 64;   // 0..7
    const int o = bb * 64 + (tid >> 2);    // output col 0..511
    const int seg = tid & 3;               // i-range quarter
    float wq[8];
    #pragma unroll
    for (int q = 0; q < 8; ++q) wq[q] = W_out[o * 8 + q];
    #pragma unroll 8
    for (int ii = 0; ii < 64; ++ii) {
      int i = seg * 64 + ii;
      float s = 0.f;
      #pragma unroll
      for (int q = 0; q < 8; ++q)
        s += ((i >> (7 - q)) & 1) ? -wq[q] : wq[q];
      unsigned short h = f2bf(s);
      unsigned short l = f2bf(s - bf2f(h));
      Mthi[o * MTS + i] = h;
      Mtlo[o * MTS + i] = l;
    }
    return;
  }

  // ---------------- encoding + psi_in ----------------
  const int b = (int)(blockIdx.x - 72) * 4 + (tid >> 6);
  if (b >= B) return;

  float xv[8];
  #pragma unroll
  for (int j = 0; j < 8; ++j) xv[j] = x[b * 512 + j * 64 + lane];

  float acc[8];
  #pragma unroll
  for (int q = 0; q < 8; ++q) {
    float s = 0.f;
    #pragma unroll
    for (int j = 0; j < 8; ++j)
      s = fmaf(xv[j], W_in[q * 512 + j * 64 + lane], s);
    acc[q] = s;
  }
  #pragma unroll
  for (int m = 1; m < 64; m <<= 1) {
    #pragma unroll
    for (int q = 0; q < 8; ++q) acc[q] += __shfl_xor(acc[q], m, 64);
  }

  float cq[8], sq[8];
  #pragma unroll
  for (int q = 0; q < 8; ++q) {
    float e  = __expf(2.f * acc[q]);
    float th = 1.f - __fdividef(2.f, e + 1.f);  // tanh
    float h  = 1.57079632679489662f * th;       // (pi/2) * tanh
    cq[q] = __cosf(h);
    sq[q] = __sinf(h);
  }

  float base = 1.f;
  #pragma unroll
  for (int q = 0; q < 6; ++q)
    base *= ((lane >> (5 - q)) & 1) ? sq[q] : cq[q];

  __hip_bfloat16 h4[4];
  h4[0] = __float2bfloat16(base * cq[6] * cq[7]);
  h4[1] = __float2bfloat16(base * cq[6] * sq[7]);
  h4[2] = __float2bfloat16(base * sq[6] * cq[7]);
  h4[3] = __float2bfloat16(base * sq[6] * sq[7]);
  uint2 pk = *reinterpret_cast<uint2*>(h4);
  *reinterpret_cast<uint2*>(psi + (size_t)b * PSIS + lane * 4) = pk;
}

__global__ __launch_bounds__(256, 1) void k2_kernel(
    const __hip_bfloat16* __restrict__ psi, const __hip_bfloat16* __restrict__ Bt,
    const unsigned short* __restrict__ Mthi,
    const unsigned short* __restrict__ Mtlo, float* __restrict__ out) {
  __shared__ unsigned short P_lds[32 * PLS];
  const int tid = threadIdx.x;
  const int lane = tid & 63;
  const int w = tid >> 6;
  const int rowbase = blockIdx.x * 32;
  const int cl = lane & 15;  // col-lane / A-row lane
  const int kg = lane >> 4;  // k-group
  const int wcol = w * 128;

  const short* psis = (const short*)psi;
  const short* Bts  = (const short*)Bt;

  // ---- G2: psiout = psi @ Bt^T ----
  bf16x8 Af[2][8];
  #pragma unroll
  for (int rt = 0; rt < 2; ++rt)
    #pragma unroll
    for (int kb = 0; kb < 8; ++kb)
      Af[rt][kb] = *(const bf16x8*)(psis +
          (size_t)(rowbase + rt * 16 + cl) * PSIS + kb * 32 + kg * 8);

  f32x4 acc[2][8];
  #pragma unroll
  for (int rt = 0; rt < 2; ++rt)
    #pragma unroll
    for (int ct = 0; ct < 8; ++ct) acc[rt][ct] = (f32x4){0.f, 0.f, 0.f, 0.f};

  #pragma unroll
  for (int ct = 0; ct < 8; ++ct) {
    const short* bp = Bts + (size_t)(wcol + ct * 16 + cl) * BTS + kg * 8;
    bf16x8 Bf[8];
    #pragma unroll
    for (int kb = 0; kb < 8; ++kb) Bf[kb] = *(const bf16x8*)(bp + kb * 32);
    #pragma unroll
    for (int kb = 0; kb < 8; ++kb) {
      acc[0][ct] = __builtin_amdgcn_mfma_f32_16x16x32_bf16(Af[0][kb], Bf[kb],
                                                           acc[0][ct], 0, 0, 0);
      acc[1][ct] = __builtin_amdgcn_mfma_f32_16x16x32_bf16(Af[1][kb], Bf[kb],
                                                           acc[1][ct], 0, 0, 0);
    }
  }

  // ---- P = re^2 + im^2 -> P_lds (bf16). Pair (2i, 2i+1) via one shfl. ----
  const bool wr = (cl & 1) == 0;
  const int ibase = (wcol >> 1) + (cl >> 1);  // + ct*8
  #pragma unroll
  for (int ct = 0; ct < 8; ++ct) {
    #pragma unroll
    for (int rt = 0; rt < 2; ++rt) {
      #pragma unroll
      for (int jr = 0; jr < 4; ++jr) {
        float v = acc[rt][ct][jr];
        v = v * v;
        float P = v + __shfl_xor(v, 1, 64);
        if (wr) {
          int row = rt * 16 + kg * 4 + jr;
          P_lds[row * PLS + ibase + ct * 8] = f2bf(P);
        }
      }
    }
  }
  __syncthreads();

  // ---- G3: out = P @ M  (M = Mhi + Mlo) ----
  bf16x8 Pf[2][8];
  #pragma unroll
  for (int rt = 0; rt < 2; ++rt)
    #pragma unroll
    for (int kb = 0; kb < 8; ++kb)
      Pf[rt][kb] = *(const bf16x8*)((const short*)P_lds +
          (rt * 16 + cl) * PLS + kb * 32 + kg * 8);

  f32x4 acc3[2][8];
  #pragma unroll
  for (int rt = 0; rt < 2; ++rt)
    #pragma unroll
    for (int ct = 0; ct < 8; ++ct) acc3[rt][ct] = (f32x4){0.f, 0.f, 0.f, 0.f};

  const short* Mhs = (const short*)Mthi;
  const short* Mls = (const short*)Mtlo;
  #pragma unroll
  for (int ct = 0; ct < 8; ++ct) {
    const size_t mo = (size_t)(wcol + ct * 16 + cl) * MTS + kg * 8;
    #pragma unroll
    for (int kb = 0; kb < 8; ++kb) {
      bf16x8 mh = *(const bf16x8*)(Mhs + mo + kb * 32);
      bf16x8 ml = *(const bf16x8*)(Mls + mo + kb * 32);
      acc3[0][ct] = __builtin_amdgcn_mfma_f32_16x16x32_bf16(Pf[0][kb], mh,
                                                            acc3[0][ct], 0, 0, 0);
      acc3[0][ct] = __builtin_amdgcn_mfma_f32_16x16x32_bf16(Pf[0][kb], ml,
                                                            acc3[0][ct], 0, 0, 0);
      acc3[1][ct] = __builtin_amdgcn_mfma_f32_16x16x32_bf16(Pf[1][kb], mh,
                                                            acc3[1][ct], 0, 0, 0);
      acc3[1][ct] = __builtin_amdgcn_mfma_f32_16x16x32_bf16(Pf[1][kb], ml,
                                                            acc3[1][ct], 0, 0, 0);
    }
  }

  // ---- direct C-fragment store: out[row][col] ----
  #pragma unroll
  for (int ct = 0; ct < 8; ++ct) {
    #pragma unroll
    for (int rt = 0; rt < 2; ++rt) {
      #pragma unroll
      for (int jr = 0; jr < 4; ++jr) {
        int row = rowbase + rt * 16 + kg * 4 + jr;
        out[(size_t)row * 512 + wcol + ct * 16 + cl] = acc3[rt][ct][jr];
      }
    }
  }
}

extern "C" void kernel_launch(void* const* d_in, const int* in_sizes, int n_in,
                              void* d_out, int out_size, void* d_ws, size_t ws_size,
                              hipStream_t stream) {
  const float* x     = (const float*)d_in[0];  // (B, 512)
  const float* W_in  = (const float*)d_in[1];  // (8, 512)
  const float* W_out = (const float*)d_in[2];  // (512, 8)
  const float* theta = (const float*)d_in[3];  // (4, 8, 3)
  float* out = (float*)d_out;

  const int B = in_sizes[0] / 512;  // 8192
  const size_t matBytes = (size_t)512 * 288 * sizeof(short);  // 294912 B

  __hip_bfloat16* Bt   = (__hip_bfloat16*)d_ws;
  unsigned short* Mthi = (unsigned short*)((char*)d_ws + matBytes);
  unsigned short* Mtlo = (unsigned short*)((char*)d_ws + 2 * matBytes);
  __hip_bfloat16* psi  = (__hip_bfloat16*)((char*)d_ws + 3 * matBytes);

  hipLaunchKernelGGL(k01_kernel, dim3(72 + B / 4), dim3(256), 0, stream,
                     x, W_in, W_out, theta, Bt, Mthi, Mtlo, psi, B);
  hipLaunchKernelGGL(k2_kernel, dim3(B / 32), dim3(256), 0, stream,
                     psi, Bt, Mthi, Mtlo, out);
}

// Round 10
// 33.335 us; speedup vs baseline: 1.5051x; 1.5051x over previous
//
#include <hip/hip_runtime.h>
#include <hip/hip_bf16.h>
#include <math.h>

// ---------------------------------------------------------------------------
// HybridQuantumLinear via fixed-unitary GEMM (R8 + fragment-order storage).
//   k01: blocks 0..63 build U -> BtF (fragment order, see below);
//        blocks 64.. encode: enc=tanh(x@W_in^T)*pi -> psiF (fragment order).
//   k2:  256 blocks x 4 waves; block = 32 batch rows; wave = 128 output cols.
//        psi_out = psi @ Bt^T via MFMA 16x16x32 (K=256, N=512);
//        P_i = re^2+im^2 ; z_q = sum sign_q(i) P_i ; out = z @ W_out^T.
// Fragment order: F[tile16][kb][lane][8] shorts, where a wave's
// mfma_f32_16x16x32_bf16 fragment for (tile, kb) is exactly the contiguous
// 64-lane x 16B slab -> every k2 load is one fully-coalesced 1KB stream
// (vs 16 scattered lines with row-major 576B-stride layout in R8).
// A-frag: lane l holds row tile*16 + l%16, k = kb*32 + (l/16)*8 + e.
// B-frag: lane l holds col tile*16 + l%16 (output n), same k mapping.
// Amp index i: bit(7-q) = qubit q. In U-build, i = lane*4 + kk.
// ---------------------------------------------------------------------------

typedef __attribute__((ext_vector_type(8))) short bf16x8;
typedef __attribute__((ext_vector_type(4))) float f32x4;

static __device__ __forceinline__ unsigned short f2bf(float f) {
  __hip_bfloat16 h = __float2bfloat16(f);
  return *reinterpret_cast<unsigned short*>(&h);
}

__device__ __forceinline__ float2 shfl_xor_f2(float2 v, int m) {
  float2 r;
  r.x = __shfl_xor(v.x, m, 64);
  r.y = __shfl_xor(v.y, m, 64);
  return r;
}
// acc += u*v (complex)
__device__ __forceinline__ float2 cfma(float2 u, float2 v, float2 acc) {
  acc.x = fmaf(u.x, v.x, fmaf(-u.y, v.y, acc.x));
  acc.y = fmaf(u.x, v.y, fmaf(u.y, v.x, acc.y));
  return acc;
}

// general 2x2 gate on qubit q
__device__ __forceinline__ void apply_gate(float2 (&a)[4], int q, float2 u00,
                                           float2 u01, float2 u10, float2 u11,
                                           int lane) {
  const float2 z0 = make_float2(0.f, 0.f);
  if (q == 7) {  // amp bit 0: pairs (0,1),(2,3)
    float2 n0 = cfma(u00, a[0], cfma(u01, a[1], z0));
    float2 n1 = cfma(u10, a[0], cfma(u11, a[1], z0));
    float2 n2 = cfma(u00, a[2], cfma(u01, a[3], z0));
    float2 n3 = cfma(u10, a[2], cfma(u11, a[3], z0));
    a[0] = n0; a[1] = n1; a[2] = n2; a[3] = n3;
  } else if (q == 6) {  // amp bit 1: pairs (0,2),(1,3)
    float2 n0 = cfma(u00, a[0], cfma(u01, a[2], z0));
    float2 n2 = cfma(u10, a[0], cfma(u11, a[2], z0));
    float2 n1 = cfma(u00, a[1], cfma(u01, a[3], z0));
    float2 n3 = cfma(u10, a[1], cfma(u11, a[3], z0));
    a[0] = n0; a[1] = n1; a[2] = n2; a[3] = n3;
  } else {  // lane bit (5-q)
    int m = 1 << (5 - q);
    bool b = (lane >> (5 - q)) & 1;
    float2 ca = b ? u11 : u00;
    float2 cp = b ? u10 : u01;
    #pragma unroll
    for (int k = 0; k < 4; ++k) {
      float2 p = shfl_xor_f2(a[k], m);
      a[k] = cfma(ca, a[k], cfma(cp, p, z0));
    }
  }
}

// CNOT(control q, target q+1)
__device__ __forceinline__ void apply_cnot(float2 (&a)[4], int q, int lane) {
  if (q <= 4) {
    int m = 1 << (4 - q);
    bool ctrl = (lane >> (5 - q)) & 1;
    #pragma unroll
    for (int k = 0; k < 4; ++k) {
      float2 p = shfl_xor_f2(a[k], m);
      a[k].x = ctrl ? p.x : a[k].x;
      a[k].y = ctrl ? p.y : a[k].y;
    }
  } else if (q == 5) {  // control = lane bit 0, target = k bit 1
    bool ct = lane & 1;
    float2 n0 = ct ? a[2] : a[0];
    float2 n1 = ct ? a[3] : a[1];
    float2 n2 = ct ? a[0] : a[2];
    float2 n3 = ct ? a[1] : a[3];
    a[0] = n0; a[1] = n1; a[2] = n2; a[3] = n3;
  } else {  // q == 6: control = k bit 1, target = k bit 0
    float2 t = a[2]; a[2] = a[3]; a[3] = t;
  }
}

__global__ __launch_bounds__(256) void k01_kernel(
    const float* __restrict__ x, const float* __restrict__ W_in,
    const float* __restrict__ theta, unsigned short* __restrict__ BtF,
    unsigned short* __restrict__ psiF, int B) {
  __shared__ float mats[32 * 8];
  const int tid = threadIdx.x;
  const int lane = tid & 63;

  if (blockIdx.x < 64) {
    // ---------------- U-build: fused gate matrices, then basis-state sim ----
    if (tid < 32) {
      int l = tid >> 3, q = tid & 7;
      const float* th = theta + (l * 8 + q) * 3;
      float h1 = 0.5f * th[0], h2 = 0.5f * th[1], h3 = 0.5f * th[2];
      float c1 = cosf(h1), s1 = sinf(h1);
      float c2 = cosf(h2), s2 = sinf(h2);
      float c3 = cosf(h3), s3 = sinf(h3);
      // M = RY*RX
      float m00r = c2 * c1, m00i = s2 * s1;
      float m01r = -s2 * c1, m01i = -c2 * s1;
      float m10r = s2 * c1, m10i = -c2 * s1;
      float m11r = c1 * c2, m11i = -s1 * s2;
      // U = RZ*M: row0 *= (c3 - i s3), row1 *= (c3 + i s3)
      float* o = &mats[tid * 8];
      o[0] = c3 * m00r + s3 * m00i;  o[1] = c3 * m00i - s3 * m00r;
      o[2] = c3 * m01r + s3 * m01i;  o[3] = c3 * m01i - s3 * m01r;
      o[4] = c3 * m10r - s3 * m10i;  o[5] = c3 * m10i + s3 * m10r;
      o[6] = c3 * m11r - s3 * m11i;  o[7] = c3 * m11i + s3 * m11r;
    }
    __syncthreads();

    const int j = blockIdx.x * 4 + (tid >> 6);  // basis column (= k index)
    float2 a[4];
    #pragma unroll
    for (int k = 0; k < 4; ++k)
      a[k] = make_float2((lane * 4 + k == j) ? 1.f : 0.f, 0.f);

    #pragma unroll
    for (int l = 0; l < 4; ++l) {
      #pragma unroll
      for (int q = 0; q < 8; ++q) {
        const float* m = &mats[(l * 8 + q) * 8];
        float2 u00 = make_float2(m[0], m[1]);
        float2 u01 = make_float2(m[2], m[3]);
        float2 u10 = make_float2(m[4], m[5]);
        float2 u11 = make_float2(m[6], m[7]);
        apply_gate(a, q, u00, u01, u10, u11, lane);
      }
      #pragma unroll
      for (int i = (l & 1); i < 7; i += 2) apply_cnot(a, i, lane);
    }
    // BtF[n/16][j/32][((j%32)/8)*16 + n%16][j%8], n = 2i+c, i = lane*4+kk
    const int kb = j >> 5, kg7 = (j & 31) >> 3, e = j & 7;
    #pragma unroll
    for (int kk = 0; kk < 4; ++kk) {
      int i = lane * 4 + kk;
      #pragma unroll
      for (int c = 0; c < 2; ++c) {
        int n = 2 * i + c;
        float v = c ? a[kk].y : a[kk].x;
        size_t addr = (size_t)(((n >> 4) * 8 + kb) * 512) +
                      (kg7 * 16 + (n & 15)) * 8 + e;
        BtF[addr] = f2bf(v);
      }
    }
    return;
  }

  // ---------------- encoding + psi_in ----------------
  const int b = (int)(blockIdx.x - 64) * 4 + (tid >> 6);
  if (b >= B) return;

  float xv[8];
  #pragma unroll
  for (int j = 0; j < 8; ++j) xv[j] = x[b * 512 + j * 64 + lane];

  float acc[8];
  #pragma unroll
  for (int q = 0; q < 8; ++q) {
    float s = 0.f;
    #pragma unroll
    for (int j = 0; j < 8; ++j)
      s = fmaf(xv[j], W_in[q * 512 + j * 64 + lane], s);
    acc[q] = s;
  }
  #pragma unroll
  for (int m = 1; m < 64; m <<= 1) {
    #pragma unroll
    for (int q = 0; q < 8; ++q) acc[q] += __shfl_xor(acc[q], m, 64);
  }

  float cq[8], sq[8];
  #pragma unroll
  for (int q = 0; q < 8; ++q) {
    float e  = __expf(2.f * acc[q]);
    float th = 1.f - __fdividef(2.f, e + 1.f);  // tanh
    float h  = 1.57079632679489662f * th;       // (pi/2) * tanh
    cq[q] = __cosf(h);
    sq[q] = __sinf(h);
  }

  float base = 1.f;
  #pragma unroll
  for (int q = 0; q < 6; ++q)
    base *= ((lane >> (5 - q)) & 1) ? sq[q] : cq[q];

  __hip_bfloat16 h4[4];
  h4[0] = __float2bfloat16(base * cq[6] * cq[7]);
  h4[1] = __float2bfloat16(base * cq[6] * sq[7]);
  h4[2] = __float2bfloat16(base * sq[6] * cq[7]);
  h4[3] = __float2bfloat16(base * sq[6] * sq[7]);
  uint2 pk = *reinterpret_cast<uint2*>(h4);
  // lane holds k = lane*4 .. lane*4+3 of row b:
  // psiF[b/16][lane/8][((lane%8)/2)*16 + b%16][(lane%2)*4], 8B store
  size_t addr = (size_t)(((b >> 4) * 8 + (lane >> 3)) * 512) +
                (((lane & 7) >> 1) * 16 + (b & 15)) * 8 + (lane & 1) * 4;
  *reinterpret_cast<uint2*>(psiF + addr) = pk;
}

__global__ __launch_bounds__(256, 1) void k2_kernel(
    const unsigned short* __restrict__ psiF,
    const unsigned short* __restrict__ BtF,
    const float* __restrict__ W_out, float* __restrict__ out) {
  __shared__ float z_lds[4][32][8];
  __shared__ float z_final[32][8];
  const int tid = threadIdx.x;
  const int lane = tid & 63;
  const int w = tid >> 6;
  const int rowbase = blockIdx.x * 32;
  const int cl = lane & 15;  // col-lane / A-row lane
  const int kg = lane >> 4;  // k-group

  const short* psis = (const short*)psiF;
  const short* Bts  = (const short*)BtF;

  // A fragments: contiguous slab per (rowtile, kb)
  bf16x8 Af[2][8];
  #pragma unroll
  for (int rt = 0; rt < 2; ++rt)
    #pragma unroll
    for (int kb = 0; kb < 8; ++kb)
      Af[rt][kb] = *(const bf16x8*)(psis +
          (size_t)((((rowbase >> 4) + rt) * 8 + kb) * 512) + lane * 8);

  const int wcol = w * 128;
  f32x4 acc[2][8];
  #pragma unroll
  for (int rt = 0; rt < 2; ++rt)
    #pragma unroll
    for (int ct = 0; ct < 8; ++ct) acc[rt][ct] = (f32x4){0.f, 0.f, 0.f, 0.f};

  #pragma unroll
  for (int ct = 0; ct < 8; ++ct) {
    const short* bp = Bts +
        (size_t)((((wcol >> 4) + ct) * 8) * 512) + lane * 8;
    bf16x8 Bf[8];
    #pragma unroll
    for (int kb = 0; kb < 8; ++kb) Bf[kb] = *(const bf16x8*)(bp + kb * 512);
    #pragma unroll
    for (int kb = 0; kb < 8; ++kb) {
      acc[0][ct] = __builtin_amdgcn_mfma_f32_16x16x32_bf16(Af[0][kb], Bf[kb],
                                                           acc[0][ct], 0, 0, 0);
      acc[1][ct] = __builtin_amdgcn_mfma_f32_16x16x32_bf16(Af[1][kb], Bf[kb],
                                                           acc[1][ct], 0, 0, 0);
    }
  }

  // ---- epilogue: P_i = re^2+im^2, z_q += sign * P. Even lanes do q0..3,
  // odd lanes q4..7 (partner lane holds the other component of the same i).
  float zacc[2][4][4];
  #pragma unroll
  for (int rt = 0; rt < 2; ++rt)
    #pragma unroll
    for (int u = 0; u < 4; ++u)
      #pragma unroll
      for (int jr = 0; jr < 4; ++jr) zacc[rt][u][jr] = 0.f;

  #pragma unroll
  for (int ct = 0; ct < 8; ++ct) {
    int n = wcol + ct * 16 + cl;
    int i = n >> 1;
    int ib = (lane & 1) ? (i & 15) : (i >> 4);
    float s[4];
    #pragma unroll
    for (int u = 0; u < 4; ++u)
      s[u] = ((ib >> (3 - u)) & 1) ? -1.f : 1.f;
    #pragma unroll
    for (int rt = 0; rt < 2; ++rt) {
      #pragma unroll
      for (int jr = 0; jr < 4; ++jr) {
        float v = acc[rt][ct][jr];
        v = v * v;
        float P = v + __shfl_xor(v, 1, 64);
        #pragma unroll
        for (int u = 0; u < 4; ++u)
          zacc[rt][u][jr] = fmaf(s[u], P, zacc[rt][u][jr]);
      }
    }
  }

  // reduce over same-parity col-lanes (lane bits 1..3)
  #pragma unroll
  for (int m = 2; m <= 8; m <<= 1)
    #pragma unroll
    for (int rt = 0; rt < 2; ++rt)
      #pragma unroll
      for (int u = 0; u < 4; ++u)
        #pragma unroll
        for (int jr = 0; jr < 4; ++jr)
          zacc[rt][u][jr] += __shfl_xor(zacc[rt][u][jr], m, 64);

  if (cl <= 1) {
    #pragma unroll
    for (int rt = 0; rt < 2; ++rt)
      #pragma unroll
      for (int u = 0; u < 4; ++u)
        #pragma unroll
        for (int jr = 0; jr < 4; ++jr)
          z_lds[w][rt * 16 + kg * 4 + jr][(lane & 1) * 4 + u] = zacc[rt][u][jr];
  }
  __syncthreads();

  {  // sum the 4 wave-partials
    int r = tid >> 3, q = tid & 7;
    z_final[r][q] = z_lds[0][r][q] + z_lds[1][r][q] + z_lds[2][r][q] +
                    z_lds[3][r][q];
  }
  __syncthreads();

  // ---- out = z @ W_out^T ----
  const int o0 = tid, o1 = 256 + tid;
  float4 wa0 = *(const float4*)(W_out + o0 * 8);
  float4 wb0 = *(const float4*)(W_out + o0 * 8 + 4);
  float4 wa1 = *(const float4*)(W_out + o1 * 8);
  float4 wb1 = *(const float4*)(W_out + o1 * 8 + 4);
  #pragma unroll 4
  for (int r = 0; r < 32; ++r) {
    float4 z0 = *(const float4*)&z_final[r][0];
    float4 z1 = *(const float4*)&z_final[r][4];
    float d0 = wa0.x * z0.x + wa0.y * z0.y + wa0.z * z0.z + wa0.w * z0.w +
               wb0.x * z1.x + wb0.y * z1.y + wb0.z * z1.z + wb0.w * z1.w;
    float d1 = wa1.x * z0.x + wa1.y * z0.y + wa1.z * z0.z + wa1.w * z0.w +
               wb1.x * z1.x + wb1.y * z1.y + wb1.z * z1.z + wb1.w * z1.w;
    out[(size_t)(rowbase + r) * 512 + o0] = d0;
    out[(size_t)(rowbase + r) * 512 + o1] = d1;
  }
}

extern "C" void kernel_launch(void* const* d_in, const int* in_sizes, int n_in,
                              void* d_out, int out_size, void* d_ws, size_t ws_size,
                              hipStream_t stream) {
  const float* x     = (const float*)d_in[0];  // (B, 512)
  const float* W_in  = (const float*)d_in[1];  // (8, 512)
  const float* W_out = (const float*)d_in[2];  // (512, 8)
  const float* theta = (const float*)d_in[3];  // (4, 8, 3)
  float* out = (float*)d_out;

  const int B = in_sizes[0] / 512;  // 8192
  // BtF: 32 coltiles x 8 kb x 512 shorts = 256 KiB
  const size_t btBytes = (size_t)32 * 8 * 512 * sizeof(short);

  unsigned short* BtF  = (unsigned short*)d_ws;
  unsigned short* psiF = (unsigned short*)((char*)d_ws + btBytes);

  hipLaunchKernelGGL(k01_kernel, dim3(64 + B / 4), dim3(256), 0, stream,
                     x, W_in, theta, BtF, psiF, B);
  hipLaunchKernelGGL(k2_kernel, dim3(B / 32), dim3(256), 0, stream,
                     psiF, BtF, W_out, out);
}